// Round 3
// baseline (56.945 us; speedup 1.0000x reference)
//
#include <hip/hip_runtime.h>
#include <hip/hip_bf16.h>
#include <math.h>

// Problem constants (match reference).
#define B_SZ   2048
#define K_MAIN 511
#define K_OUT  512
#define D_SZ   64

// Workspace layout (floats):
//   coef  [0 .. K_MAIN*D_SZ)  = (softmax(logits)+1e-10)*exp(clip(ld)) per (k,d)
//   betas [K_MAIN*D_SZ .. +K_MAIN)
#define WS_COEF  0
#define WS_BETAS (K_MAIN * D_SZ)

typedef float f4v __attribute__((ext_vector_type(4)));

__device__ __forceinline__ float softplus_clip(float x) {
    float sp = (x > 20.f) ? x : log1pf(expf(x));
    return fminf(fmaxf(sp, 0.f), 10.f);
}

// K_MAIN blocks x 64 threads (one wave each). Block k: per-k coefficients.
// Blocks 0..31 additionally fill the null output column (b = blk*64+lane).
__global__ void precompute_kernel(const float* __restrict__ log_density,      // (K_MAIN, D)
                                  const float* __restrict__ logits,           // (K_MAIN, D)
                                  const float* __restrict__ beta_raw,         // (K_MAIN,)
                                  const float* __restrict__ null_log_density, // (D,)
                                  const float* __restrict__ null_logits,      // (D,)
                                  const float* __restrict__ null_beta_raw,    // (1,)
                                  const float* __restrict__ null_vals,        // (B,)
                                  float* __restrict__ ws,
                                  float* __restrict__ out) {                  // (B, K_OUT)
    const int k    = blockIdx.x;
    const int lane = threadIdx.x;  // 0..63, one full wave

    // --- per-k coefficient row ---
    {
        float lg = logits[k * D_SZ + lane];
        float m = lg;
        #pragma unroll
        for (int off = 1; off < 64; off <<= 1) m = fmaxf(m, __shfl_xor(m, off));
        float e = expf(lg - m);
        float s = e;
        #pragma unroll
        for (int off = 1; off < 64; off <<= 1) s += __shfl_xor(s, off);
        float w = e / s;                                   // softmax
        float ld = fminf(fmaxf(log_density[k * D_SZ + lane], -10.f), 0.f);
        // exp(log(w+1e-10) + ld) == (w+1e-10)*exp(ld); exp(M) folded exactly.
        ws[WS_COEF + k * D_SZ + lane] = (w + 1e-10f) * expf(ld);
        if (lane == 0) {
            ws[WS_BETAS + k] = softplus_clip(beta_raw[k]);
        }
    }

    // --- null column (blocks 0..31 cover B=2048 rows, 64 each) ---
    if (k < (B_SZ / 64)) {
        float lg = null_logits[lane];
        float m = lg;
        #pragma unroll
        for (int off = 1; off < 64; off <<= 1) m = fmaxf(m, __shfl_xor(m, off));
        float e = expf(lg - m);
        float s = e;
        #pragma unroll
        for (int off = 1; off < 64; off <<= 1) s += __shfl_xor(s, off);
        // every lane recomputes softmax[0] from the broadcast scalar
        float w0 = expf(null_logits[0] - m) / s;
        float ld0 = fminf(fmaxf(null_log_density[0], -10.f), 0.f);
        float c_null = (w0 + 1e-10f) * expf(ld0);
        float nbeta  = softplus_clip(null_beta_raw[0]);
        const int b = k * 64 + lane;
        out[(size_t)b * K_OUT + K_MAIN] = c_null * null_vals[b] - nbeta;
    }
}

// Main streaming kernel. One wave handles 16 consecutive rows (4 chunks of 4)
// per iteration: lane -> row sub = lane>>4, d0 = (lane&15)*4. Four independent
// nontemporal float4 loads per lane per iteration (4 KiB contiguous per wave).
// vals is streamed (nt, zero reuse); coef stays L2-resident.
__global__ void __launch_bounds__(256)
main_kernel(const float* __restrict__ vals,   // (B, K_MAIN, D)
            const float* __restrict__ ws,
            float* __restrict__ out) {        // (B, K_OUT)
    const float* __restrict__ coef  = ws + WS_COEF;
    const float* __restrict__ betas = ws + WS_BETAS;

    const unsigned tid     = blockIdx.x * blockDim.x + threadIdx.x;
    const unsigned lane    = threadIdx.x & 63u;
    const unsigned wave    = tid >> 6;
    const unsigned nwaves  = (gridDim.x * blockDim.x) >> 6;
    const unsigned sub     = lane >> 4;          // 0..3 : row within chunk
    const unsigned d0      = (lane & 15u) << 2;  // 0,4,...,60

    const unsigned total_rows = B_SZ * K_MAIN;   // 1,046,528 (divisible by 16)
    const unsigned nquads     = total_rows >> 4; // 65,408 groups of 16 rows

    for (unsigned q = wave; q < nquads; q += nwaves) {
        const unsigned r0 = (q << 4) + sub;      // rows r0, r0+4, r0+8, r0+12

        // 4 independent streaming loads, issued back-to-back
        const f4v v0 = __builtin_nontemporal_load(
            reinterpret_cast<const f4v*>(vals + (size_t)r0 * D_SZ + d0));
        const f4v v1 = __builtin_nontemporal_load(
            reinterpret_cast<const f4v*>(vals + (size_t)(r0 + 4) * D_SZ + d0));
        const f4v v2 = __builtin_nontemporal_load(
            reinterpret_cast<const f4v*>(vals + (size_t)(r0 + 8) * D_SZ + d0));
        const f4v v3 = __builtin_nontemporal_load(
            reinterpret_cast<const f4v*>(vals + (size_t)(r0 + 12) * D_SZ + d0));

        // k/b for the 4 rows: one div-mod + incremental branchless wrap
        unsigned k0 = r0 % K_MAIN;               // magic-mul
        unsigned b0 = r0 / K_MAIN;
        unsigned k1 = k0 + 4, b1 = b0; if (k1 >= K_MAIN) { k1 -= K_MAIN; ++b1; }
        unsigned k2 = k1 + 4, b2 = b1; if (k2 >= K_MAIN) { k2 -= K_MAIN; ++b2; }
        unsigned k3 = k2 + 4, b3 = b2; if (k3 >= K_MAIN) { k3 -= K_MAIN; ++b3; }

        const f4v c0 = *reinterpret_cast<const f4v*>(coef + (size_t)k0 * D_SZ + d0);
        const f4v c1 = *reinterpret_cast<const f4v*>(coef + (size_t)k1 * D_SZ + d0);
        const f4v c2 = *reinterpret_cast<const f4v*>(coef + (size_t)k2 * D_SZ + d0);
        const f4v c3 = *reinterpret_cast<const f4v*>(coef + (size_t)k3 * D_SZ + d0);

        float p0 = v0.x * c0.x + v0.y * c0.y + v0.z * c0.z + v0.w * c0.w;
        float p1 = v1.x * c1.x + v1.y * c1.y + v1.z * c1.z + v1.w * c1.w;
        float p2 = v2.x * c2.x + v2.y * c2.y + v2.z * c2.z + v2.w * c2.w;
        float p3 = v3.x * c3.x + v3.y * c3.y + v3.z * c3.z + v3.w * c3.w;

        p0 += __shfl_xor(p0, 1);  p1 += __shfl_xor(p1, 1);
        p2 += __shfl_xor(p2, 1);  p3 += __shfl_xor(p3, 1);
        p0 += __shfl_xor(p0, 2);  p1 += __shfl_xor(p1, 2);
        p2 += __shfl_xor(p2, 2);  p3 += __shfl_xor(p3, 2);
        p0 += __shfl_xor(p0, 4);  p1 += __shfl_xor(p1, 4);
        p2 += __shfl_xor(p2, 4);  p3 += __shfl_xor(p3, 4);
        p0 += __shfl_xor(p0, 8);  p1 += __shfl_xor(p1, 8);
        p2 += __shfl_xor(p2, 8);  p3 += __shfl_xor(p3, 8);

        if ((lane & 15u) == 0u) {
            out[(size_t)b0 * K_OUT + k0] = p0 - betas[k0];
            out[(size_t)b1 * K_OUT + k1] = p1 - betas[k1];
            out[(size_t)b2 * K_OUT + k2] = p2 - betas[k2];
            out[(size_t)b3 * K_OUT + k3] = p3 - betas[k3];
        }
    }
}

extern "C" void kernel_launch(void* const* d_in, const int* in_sizes, int n_in,
                              void* d_out, int out_size, void* d_ws, size_t ws_size,
                              hipStream_t stream) {
    const float* vals             = (const float*)d_in[0];
    const float* log_density      = (const float*)d_in[1];
    const float* logits           = (const float*)d_in[2];
    const float* beta_raw         = (const float*)d_in[3];
    const float* null_vals        = (const float*)d_in[4];
    const float* null_log_density = (const float*)d_in[5];
    const float* null_logits      = (const float*)d_in[6];
    const float* null_beta_raw    = (const float*)d_in[7];

    float* out = (float*)d_out;
    float* ws  = (float*)d_ws;

    precompute_kernel<<<K_MAIN, 64, 0, stream>>>(log_density, logits, beta_raw,
                                                 null_log_density, null_logits,
                                                 null_beta_raw, null_vals, ws, out);

    main_kernel<<<4096, 256, 0, stream>>>(vals, ws, out);
}

// Round 4
// 48.895 us; speedup vs baseline: 1.1646x; 1.1646x over previous
//
#include <hip/hip_runtime.h>
#include <hip/hip_bf16.h>
#include <math.h>

// Problem constants (match reference).
#define B_SZ   2048
#define K_MAIN 511
#define K_OUT  512
#define D_SZ   64

// Workspace layout (floats):
//   coef  [0 .. K_MAIN*D_SZ)  = (softmax(logits)+1e-10)*exp(clip(ld)) per (k,d)
//   betas [K_MAIN*D_SZ .. +K_MAIN)
#define WS_COEF  0
#define WS_BETAS (K_MAIN * D_SZ)

typedef float f4v __attribute__((ext_vector_type(4)));

__device__ __forceinline__ float softplus_clip(float x) {
    float sp = (x > 20.f) ? x : log1pf(expf(x));
    return fminf(fmaxf(sp, 0.f), 10.f);
}

// K_MAIN blocks x 64 threads (one wave each). Block k: per-k coefficients.
// Blocks 0..31 additionally fill the null output column (b = blk*64+lane).
__global__ void precompute_kernel(const float* __restrict__ log_density,      // (K_MAIN, D)
                                  const float* __restrict__ logits,           // (K_MAIN, D)
                                  const float* __restrict__ beta_raw,         // (K_MAIN,)
                                  const float* __restrict__ null_log_density, // (D,)
                                  const float* __restrict__ null_logits,      // (D,)
                                  const float* __restrict__ null_beta_raw,    // (1,)
                                  const float* __restrict__ null_vals,        // (B,)
                                  float* __restrict__ ws,
                                  float* __restrict__ out) {                  // (B, K_OUT)
    const int k    = blockIdx.x;
    const int lane = threadIdx.x;  // 0..63, one full wave

    // --- per-k coefficient row ---
    {
        float lg = logits[k * D_SZ + lane];
        float m = lg;
        #pragma unroll
        for (int off = 1; off < 64; off <<= 1) m = fmaxf(m, __shfl_xor(m, off));
        float e = expf(lg - m);
        float s = e;
        #pragma unroll
        for (int off = 1; off < 64; off <<= 1) s += __shfl_xor(s, off);
        float w = e / s;                                   // softmax
        float ld = fminf(fmaxf(log_density[k * D_SZ + lane], -10.f), 0.f);
        // exp(log(w+1e-10) + ld) == (w+1e-10)*exp(ld); exp(M) folded exactly.
        ws[WS_COEF + k * D_SZ + lane] = (w + 1e-10f) * expf(ld);
        if (lane == 0) {
            ws[WS_BETAS + k] = softplus_clip(beta_raw[k]);
        }
    }

    // --- null column (blocks 0..31 cover B=2048 rows, 64 each) ---
    if (k < (B_SZ / 64)) {
        float lg = null_logits[lane];
        float m = lg;
        #pragma unroll
        for (int off = 1; off < 64; off <<= 1) m = fmaxf(m, __shfl_xor(m, off));
        float e = expf(lg - m);
        float s = e;
        #pragma unroll
        for (int off = 1; off < 64; off <<= 1) s += __shfl_xor(s, off);
        // every lane recomputes softmax[0] from the broadcast scalar
        float w0 = expf(null_logits[0] - m) / s;
        float ld0 = fminf(fmaxf(null_log_density[0], -10.f), 0.f);
        float c_null = (w0 + 1e-10f) * expf(ld0);
        float nbeta  = softplus_clip(null_beta_raw[0]);
        const int b = k * 64 + lane;
        out[(size_t)b * K_OUT + K_MAIN] = c_null * null_vals[b] - nbeta;
    }
}

// Main streaming kernel. One wave handles 16 consecutive rows (4 chunks of 4)
// per iteration: lane -> row sub = lane>>4, d0 = (lane&15)*4. Four independent
// plain float4 loads per lane per iteration (4 KiB contiguous per wave).
__global__ void __launch_bounds__(256)
main_kernel(const float* __restrict__ vals,   // (B, K_MAIN, D)
            const float* __restrict__ ws,
            float* __restrict__ out) {        // (B, K_OUT)
    const float* __restrict__ coef  = ws + WS_COEF;
    const float* __restrict__ betas = ws + WS_BETAS;

    const unsigned tid     = blockIdx.x * blockDim.x + threadIdx.x;
    const unsigned lane    = threadIdx.x & 63u;
    const unsigned wave    = tid >> 6;
    const unsigned nwaves  = (gridDim.x * blockDim.x) >> 6;
    const unsigned sub     = lane >> 4;          // 0..3 : row within chunk
    const unsigned d0      = (lane & 15u) << 2;  // 0,4,...,60

    const unsigned total_rows = B_SZ * K_MAIN;   // 1,046,528 (divisible by 16)
    const unsigned nquads     = total_rows >> 4; // 65,408 groups of 16 rows

    for (unsigned q = wave; q < nquads; q += nwaves) {
        const unsigned r0 = (q << 4) + sub;      // rows r0, r0+4, r0+8, r0+12

        // 4 independent loads, issued back-to-back
        const f4v v0 = *reinterpret_cast<const f4v*>(vals + (size_t)r0 * D_SZ + d0);
        const f4v v1 = *reinterpret_cast<const f4v*>(vals + (size_t)(r0 + 4) * D_SZ + d0);
        const f4v v2 = *reinterpret_cast<const f4v*>(vals + (size_t)(r0 + 8) * D_SZ + d0);
        const f4v v3 = *reinterpret_cast<const f4v*>(vals + (size_t)(r0 + 12) * D_SZ + d0);

        // k/b for the 4 rows: one div-mod + incremental branchless wrap
        unsigned k0 = r0 % K_MAIN;               // magic-mul
        unsigned b0 = r0 / K_MAIN;
        unsigned k1 = k0 + 4, b1 = b0; if (k1 >= K_MAIN) { k1 -= K_MAIN; ++b1; }
        unsigned k2 = k1 + 4, b2 = b1; if (k2 >= K_MAIN) { k2 -= K_MAIN; ++b2; }
        unsigned k3 = k2 + 4, b3 = b2; if (k3 >= K_MAIN) { k3 -= K_MAIN; ++b3; }

        const f4v c0 = *reinterpret_cast<const f4v*>(coef + (size_t)k0 * D_SZ + d0);
        const f4v c1 = *reinterpret_cast<const f4v*>(coef + (size_t)k1 * D_SZ + d0);
        const f4v c2 = *reinterpret_cast<const f4v*>(coef + (size_t)k2 * D_SZ + d0);
        const f4v c3 = *reinterpret_cast<const f4v*>(coef + (size_t)k3 * D_SZ + d0);

        float p0 = v0.x * c0.x + v0.y * c0.y + v0.z * c0.z + v0.w * c0.w;
        float p1 = v1.x * c1.x + v1.y * c1.y + v1.z * c1.z + v1.w * c1.w;
        float p2 = v2.x * c2.x + v2.y * c2.y + v2.z * c2.z + v2.w * c2.w;
        float p3 = v3.x * c3.x + v3.y * c3.y + v3.z * c3.z + v3.w * c3.w;

        p0 += __shfl_xor(p0, 1);  p1 += __shfl_xor(p1, 1);
        p2 += __shfl_xor(p2, 1);  p3 += __shfl_xor(p3, 1);
        p0 += __shfl_xor(p0, 2);  p1 += __shfl_xor(p1, 2);
        p2 += __shfl_xor(p2, 2);  p3 += __shfl_xor(p3, 2);
        p0 += __shfl_xor(p0, 4);  p1 += __shfl_xor(p1, 4);
        p2 += __shfl_xor(p2, 4);  p3 += __shfl_xor(p3, 4);
        p0 += __shfl_xor(p0, 8);  p1 += __shfl_xor(p1, 8);
        p2 += __shfl_xor(p2, 8);  p3 += __shfl_xor(p3, 8);

        if ((lane & 15u) == 0u) {
            out[(size_t)b0 * K_OUT + k0] = p0 - betas[k0];
            out[(size_t)b1 * K_OUT + k1] = p1 - betas[k1];
            out[(size_t)b2 * K_OUT + k2] = p2 - betas[k2];
            out[(size_t)b3 * K_OUT + k3] = p3 - betas[k3];
        }
    }
}

extern "C" void kernel_launch(void* const* d_in, const int* in_sizes, int n_in,
                              void* d_out, int out_size, void* d_ws, size_t ws_size,
                              hipStream_t stream) {
    const float* vals             = (const float*)d_in[0];
    const float* log_density      = (const float*)d_in[1];
    const float* logits           = (const float*)d_in[2];
    const float* beta_raw         = (const float*)d_in[3];
    const float* null_vals        = (const float*)d_in[4];
    const float* null_log_density = (const float*)d_in[5];
    const float* null_logits      = (const float*)d_in[6];
    const float* null_beta_raw    = (const float*)d_in[7];

    float* out = (float*)d_out;
    float* ws  = (float*)d_ws;

    precompute_kernel<<<K_MAIN, 64, 0, stream>>>(log_density, logits, beta_raw,
                                                 null_log_density, null_logits,
                                                 null_beta_raw, null_vals, ws, out);

    main_kernel<<<4096, 256, 0, stream>>>(vals, ws, out);
}